// Round 8
// baseline (415.510 us; speedup 1.0000x reference)
//
#include <hip/hip_runtime.h>

// Problem constants
#define MDIM 8192
#define IDIM 1024
#define ODIM 1024
#define D1   9            // DEGREE+1
#define KDIM (IDIM * D1)  // 9216, k = d*1024 + i ordering
#define NSTEP (KDIM / 64) // 144 k-steps

typedef _Float16 half8   __attribute__((ext_vector_type(8)));
typedef float    float4v __attribute__((ext_vector_type(4)));

#define BSCALE 256.0f     // pre-scale B into f16-normal range (exact pow2)
#define INV_BSCALE (1.0f / 256.0f)
#define USCALE 5.123105625617661f    // sqrt(17) + 1
#define H0C 0.7511255444649425f     // pi^-1/4
#define SQRT2 1.4142135623730951f

__constant__ float c1a[D1] = {0.f, 0.f, 1.0f, 0.8164965809277260f, 0.7071067811865476f,
                              0.6324555320336759f, 0.5773502691896258f, 0.5345224838248488f, 0.5f};
__constant__ float c2a[D1] = {0.f, 0.f, 0.7071067811865476f, 0.8164965809277260f, 0.8660254037844386f,
                              0.8944271909999159f, 0.9128709291752769f, 0.9258200997725514f, 0.9354143466934853f};

// ---------------------------------------------------------------------------
__device__ __forceinline__ void hermite9(float xv, float h[D1]) {
    float ax = fabsf(xv);
    float t  = __expf(-2.0f * ax);
    float th = (1.0f - t) * __builtin_amdgcn_rcpf(1.0f + t);
    th = copysignf(th, xv);
    float u = th * USCALE;
    float g = __expf(-0.5f * u * u);
    h[0] = H0C * g;
    h[1] = SQRT2 * H0C * u * g;
#pragma unroll
    for (int d = 2; d < D1; ++d) h[d] = c1a[d] * u * h[d - 1] - c2a[d] * h[d - 2];
}

// ---------------------------------------------------------------------------
// prep_all: one launch, two bodies (wave-uniform split on blockIdx).
//  blocks [0,1024):     prep_b — LDS-transpose coeffs fp32 [I][O][9] ->
//                       Bt f16 [O][K] * 256, coalesced both phases.
//  blocks [1024,5120):  prep_h — x -> full Hermite basis H f16 [8192][KDIM].
// ---------------------------------------------------------------------------
__global__ __launch_bounds__(256) void prep_all(const float* __restrict__ C,
                                                _Float16* __restrict__ Bt,
                                                const float* __restrict__ x,
                                                _Float16* __restrict__ H) {
    if (blockIdx.x < 1024) {
        __shared__ float lds[288 * 33];
        const int t  = threadIdx.x;
        const int ti = blockIdx.x & 31;
        const int to = blockIdx.x >> 5;
        const float* base = C + (size_t)ti * 32 * 9216 + (size_t)to * 32 * 9;
#pragma unroll
        for (int j = 0; j < 36; ++j) {
            int f   = t + 256 * j;
            int row = f / 288;
            int col = f - row * 288;
            lds[col * 33 + row] = base[(size_t)row * 9216 + col];
        }
        __syncthreads();
        _Float16* bb = Bt + (size_t)to * 32 * KDIM + ti * 32;
#pragma unroll
        for (int j = 0; j < 36; ++j) {
            int e   = t + 256 * j;
            int i   = e & 31;
            int odp = e >> 5;
            int ol  = odp / 9;
            int d   = odp - ol * 9;
            bb[(size_t)ol * KDIM + d * IDIM + i] = (_Float16)(lds[odp * 33 + i] * BSCALE);
        }
    } else {
        int t  = (blockIdx.x - 1024) * 256 + threadIdx.x;
        int r  = t >> 7;                 // row 0..8191
        int ig = (t & 127) << 3;         // i0
        const float* xp = x + (((size_t)r) << 10) + ig;
        float4 a0 = *(const float4*)xp;
        float4 a1 = *(const float4*)(xp + 4);
        float xv[8] = {a0.x, a0.y, a0.z, a0.w, a1.x, a1.y, a1.z, a1.w};
        float h[8][D1];
#pragma unroll
        for (int e = 0; e < 8; ++e) hermite9(xv[e], h[e]);
        _Float16* hp = H + (size_t)r * KDIM + ig;
#pragma unroll
        for (int d = 0; d < D1; ++d) {
            half8 v;
#pragma unroll
            for (int e = 0; e < 8; ++e) v[e] = (_Float16)h[e][d];
            *(half8*)(hp + (size_t)d * IDIM) = v;
        }
    }
}

// ---------------------------------------------------------------------------
// gemm_big: 256x128 block tile (85 FLOP per L2-staged byte vs 32 at 128x128 —
// L2 staging was at ~75% of its 34.5 TB/s ceiling in R1/R7, co-binding with
// MFMA). 4 waves 2x2, wave tile 128x64, acc 8x4 frags (128 VGPRs). LDS 96 KB
// (As 2x32K + Bs 2x16K) -> exactly 1 block/CU, grid 256 = full co-residency,
// zero tail. Single-barrier ring (R7): per step, barrier publishes buf[cur]
// (DMA'd one full step ago), issue DMA(s+1) into buf[nxt], then 24 ds_read +
// 64 MFMA on buf[cur]. XOR k-group swizzle (0 conflicts, measured all session).
// __launch_bounds__(256,1): full 512-VGPR budget, no spill (R5's lesson).
// ---------------------------------------------------------------------------
__global__ __launch_bounds__(256, 1) void gemm_big(
    const _Float16* __restrict__ A,    // H [8192][KDIM]
    const _Float16* __restrict__ Bt,   // [ODIM][KDIM]
    float* __restrict__ out)           // [8192][ODIM]
{
    const int tid = threadIdx.x;
    const int w = tid >> 6;
    const int l = tid & 63;
    const int bn = blockIdx.x;    // n-tile 0..7 (flat%8 = XCD -> L2-hot B panel)
    const int bm = blockIdx.y;    // m-tile 0..31

    __shared__ _Float16 As[2][256 * 64];   // 2 x 32 KB
    __shared__ _Float16 Bs[2][128 * 64];   // 2 x 16 KB

    // staging: lane l, rep r loads 16B; stored data k-group = (l&7)^(l>>3)
    const int lrow8 = l >> 3;
    const int kgrp  = (l & 7) ^ lrow8;
    const _Float16* Ag = A  + ((size_t)(bm * 256 + w * 8 + lrow8) * KDIM + kgrp * 8);
    const _Float16* Bg = Bt + ((size_t)(bn * 128 + w * 8 + lrow8) * KDIM + kgrp * 8);

    // compute-side fragment indices
    const int q   = l >> 4;
    const int m16 = l & 15;
    const int s3  = m16 & 7;
    const int wm  = w >> 1, wn = w & 1;

    float4v acc[8][4] = {};

    auto stage = [&](int buf, int k0) {
#pragma unroll
        for (int r = 0; r < 8; ++r)    // A: 256 rows
            __builtin_amdgcn_global_load_lds(
                (const __attribute__((address_space(1))) void*)(Ag + (size_t)(r * 32) * KDIM + k0),
                (__attribute__((address_space(3))) void*)((char*)&As[buf][0] + (r * 4 + w) * 1024),
                16, 0, 0);
#pragma unroll
        for (int r = 0; r < 4; ++r)    // B: 128 rows
            __builtin_amdgcn_global_load_lds(
                (const __attribute__((address_space(1))) void*)(Bg + (size_t)(r * 32) * KDIM + k0),
                (__attribute__((address_space(3))) void*)((char*)&Bs[buf][0] + (r * 4 + w) * 1024),
                16, 0, 0);
    };

    auto compute = [&](int buf) {
#pragma unroll
        for (int ko = 0; ko < 2; ++ko) {
            const int slot = (q + 4 * ko) ^ s3;
            half8 af[8], bf[4];
#pragma unroll
            for (int j = 0; j < 4; ++j)
                bf[j] = *(const half8*)&Bs[buf][(wn * 64 + j * 16 + m16) * 64 + slot * 8];
#pragma unroll
            for (int i = 0; i < 8; ++i)
                af[i] = *(const half8*)&As[buf][(wm * 128 + i * 16 + m16) * 64 + slot * 8];
#pragma unroll
            for (int i = 0; i < 8; ++i)
#pragma unroll
                for (int j = 0; j < 4; ++j)
                    acc[i][j] = __builtin_amdgcn_mfma_f32_16x16x32_f16(af[i], bf[j], acc[i][j], 0, 0, 0);
        }
    };

    // prologue: DMA step 0 into buf 0
    stage(0, 0);

    // ring: unrolled by 2 so buffer index is compile-time
    for (int s2 = 0; s2 < NSTEP; s2 += 2) {
        __syncthreads();                       // buf0 ready (DMA'd a full step ago)
        stage(1, (s2 + 1) * 64);
        compute(0);
        __syncthreads();                       // buf1 ready
        if (s2 + 2 < NSTEP) stage(0, (s2 + 2) * 64);
        compute(1);
    }

    // epilogue: D row = quad*4 + reg, col = lane&15 (m89-verified layout)
#pragma unroll
    for (int i = 0; i < 8; ++i) {
        int row = bm * 256 + wm * 128 + i * 16 + q * 4;
#pragma unroll
        for (int j = 0; j < 4; ++j) {
            int col = bn * 128 + wn * 64 + j * 16 + m16;
            float* op = out + (size_t)row * ODIM + col;
#pragma unroll
            for (int r2 = 0; r2 < 4; ++r2)
                op[(size_t)r2 * ODIM] = acc[i][j][r2] * INV_BSCALE;
        }
    }
}

// ---------------------------------------------------------------------------
// naive fallback (only if workspace can't hold Bt + H, 170 MB)
// ---------------------------------------------------------------------------
__global__ void naive_kernel(const float* __restrict__ x, const float* __restrict__ C,
                             float* __restrict__ out) {
    __shared__ float hb[IDIM * D1];
    int b = blockIdx.x;
    int tid = threadIdx.x;
    for (int i = tid; i < IDIM; i += 256) {
        float h[D1];
        hermite9(x[(size_t)b * IDIM + i], h);
#pragma unroll
        for (int d = 0; d < D1; ++d) hb[i * D1 + d] = h[d];
    }
    __syncthreads();
    for (int o = tid; o < ODIM; o += 256) {
        float acc = 0.f;
        for (int i = 0; i < IDIM; ++i) {
            const float* cp = C + ((size_t)i * ODIM + o) * D1;
            const float* hp = hb + i * D1;
#pragma unroll
            for (int d = 0; d < D1; ++d) acc += hp[d] * cp[d];
        }
        out[(size_t)b * ODIM + o] = acc;
    }
}

// ---------------------------------------------------------------------------
extern "C" void kernel_launch(void* const* d_in, const int* in_sizes, int n_in,
                              void* d_out, int out_size, void* d_ws, size_t ws_size,
                              hipStream_t stream) {
    const float* x      = (const float*)d_in[0];   // [8192][1024]
    const float* coeffs = (const float*)d_in[1];   // [1024][1024][9]
    float* out = (float*)d_out;                    // [8192][1024]

    const size_t bt_bytes = (size_t)ODIM * KDIM * sizeof(_Float16);   // 18.9 MB
    const size_t h_bytes  = (size_t)MDIM * KDIM * sizeof(_Float16);   // 151.0 MB

    if (ws_size >= bt_bytes + h_bytes) {
        _Float16* Bt = (_Float16*)d_ws;
        _Float16* H  = (_Float16*)((char*)d_ws + bt_bytes);
        hipLaunchKernelGGL(prep_all, dim3(1024 + (MDIM * IDIM) / 2048), dim3(256), 0, stream,
                           coeffs, Bt, x, H);
        hipLaunchKernelGGL(gemm_big, dim3(8, 32), dim3(256), 0, stream, H, Bt, out);
    } else {
        hipLaunchKernelGGL(naive_kernel, dim3(MDIM), dim3(256), 0, stream, x, coeffs, out);
    }
}